// Round 7
// baseline (353.585 us; speedup 1.0000x reference)
//
#include <hip/hip_runtime.h>
#include <hip/hip_bf16.h>

#define LEAKC 0.1f

__device__ __forceinline__ float lrelu(float v){ return v > 0.f ? v : LEAKC*v; }
__device__ __forceinline__ ushort f2b(float f){
  __hip_bfloat16 h = __float2bfloat16(f);
  return *reinterpret_cast<ushort*>(&h);
}

typedef __attribute__((ext_vector_type(8))) short bf16x8;
typedef __attribute__((ext_vector_type(4))) float f32x4;

// ---------------- styles ----------------
__global__ void style_kernel(const float* __restrict__ g,
                             const float* __restrict__ sp1,
                             const float* __restrict__ sp2,
                             float* __restrict__ s1, float* __restrict__ s2){
  int t = threadIdx.x;
  if (t < 64){
    int b = t >> 5, j = t & 31;
    float a = 0.f;
    for (int k=0;k<256;k++) a += g[b*256+k]*sp1[j*256+k];
    s1[t] = a;
  } else if (t < 192){
    int u = t - 64;
    int b = u >> 6, j = u & 63;
    float a = 0.f;
    for (int k=0;k<256;k++) a += g[b*256+k]*sp2[j*256+k];
    s2[u] = a;
  }
}

// ---------------- cls ----------------
__global__ void cls_kernel(const float* __restrict__ label, int* __restrict__ cls){
  int n = threadIdx.x;
  int b = n >> 7, t = n & 127;
  const float* p = label + (t*2 + b)*80;
  float best = p[0]; int bi = 0;
  for (int c=1;c<80;c++){ float v = p[c]; if (v > best){ best = v; bi = c; } }
  cls[n] = bi;
}

// ---------------- input conv 7x7 -> bf16 out ----------------
__global__ void conv_in_kernel(const float* __restrict__ x,
                               const float* __restrict__ wgt,
                               const float* __restrict__ bias,
                               ushort* __restrict__ out){
  int hw = blockIdx.x*256 + threadIdx.x;
  int y = hw >> 9, w = hw & 511;
  int b = blockIdx.z;
  int o0 = blockIdx.y * 8;
  float acc[8];
  #pragma unroll
  for (int i=0;i<8;i++) acc[i] = bias[o0+i];
  for (int kh=0;kh<7;kh++){
    const float* ip = x + (b*64 + y + kh)*512;
    #pragma unroll
    for (int kw=0;kw<7;kw++){
      int wi = w + kw - 3;
      float v = (wi>=0 && wi<512) ? ip[wi] : 0.f;
      #pragma unroll
      for (int i=0;i<8;i++) acc[i] += v * wgt[(o0+i)*49 + kh*7 + kw];
    }
  }
  #pragma unroll
  for (int i=0;i<8;i++)
    out[((b*64 + o0+i)*58 + y)*512 + w] = f2b(lrelu(acc[i]));
}

// ---------------- weight repack: wb[n][(kh*3+kw)*CM + c] = bf16(w[n][c][kh][kw]) ----------------
template<int CM,int CTOT,int COUT>
__global__ void repack_kernel(const float* __restrict__ w, ushort* __restrict__ wb){
  int i = blockIdx.x*256 + threadIdx.x;
  if (i >= COUT*9*CM) return;
  int c = i % CM; int r = i / CM; int t = r % 9; int n = r / 9;
  wb[i] = f2b(w[((size_t)n*CTOT + c)*9 + t]);
}

// ---------------- MFMA conv: 3x3, pad(0,1), BM=64 (one w-strip), BN=64, K=CM*9 ----------------
template<int CM,int WID,int HIN,int COUT,int MODE,int OUTBF>
__global__ __launch_bounds__(256) void conv_mfma(
    const ushort* __restrict__ in,   // bf16 (2,CM,HIN,WID)
    const ushort* __restrict__ Wb,   // bf16 (COUT, CM*9)
    const float*  __restrict__ mb,   // map (2,COUT,3) or bias (COUT)
    float* __restrict__ outf,
    ushort* __restrict__ outh){
  constexpr int HOUT = HIN - 2;
  constexpr int KTOT = CM*9;
  constexpr int SLABS = CM/32;
  constexpr int NST = 3*SLABS;
  __shared__ ushort A[2][66][40];
  int tid = threadIdx.x, lane = tid & 63, wave = tid >> 6;
  int mt = blockIdx.x;
  int y  = mt / (WID/64), w0 = (mt % (WID/64))*64;
  int n0 = blockIdx.y*64;
  int b  = blockIdx.z;

  f32x4 acc[4];
  #pragma unroll
  for (int nf=0;nf<4;nf++) acc[nf] = (f32x4){0.f,0.f,0.f,0.f};

  auto stage = [&](int s, int bufi){
    int kh = s / SLABS;
    int c0 = (s % SLABS)*32;
    const ushort* base = in + ((size_t)(b*CM + c0)*HIN + (y+kh))*WID;
    int c2 = (tid & 15)*2, m0v = (tid >> 4)*2*2;
    const ushort* p0 = base + (size_t)c2*HIN*WID + w0 + m0v;
    const ushort* p1 = p0 + (size_t)HIN*WID;
    ushort4 va = *(const ushort4*)p0;
    ushort4 vb = *(const ushort4*)p1;
    uint* dst = (uint*)&A[bufi][1+m0v][c2];
    dst[0]  = (uint)va.x | ((uint)vb.x << 16);
    dst[20] = (uint)va.y | ((uint)vb.y << 16);
    dst[40] = (uint)va.z | ((uint)vb.z << 16);
    dst[60] = (uint)va.w | ((uint)vb.w << 16);
    if (tid < 64){
      int c = tid & 31, side = tid >> 5;
      int w = side ? (w0 + 64) : (w0 - 1);
      ushort v = 0;
      if (w >= 0 && w < WID) v = base[(size_t)c*HIN*WID + w];
      A[bufi][side ? 65 : 0][c] = v;
    }
  };

  stage(0, 0);
  __syncthreads();
  for (int s = 0; s < NST; ++s){
    int cur = s & 1;
    if (s + 1 < NST) stage(s+1, cur ^ 1);
    int kh = s / SLABS;
    int c0 = (s % SLABS)*32;
    #pragma unroll
    for (int kw = 0; kw < 3; ++kw){
      bf16x8 a = *(bf16x8*)&A[cur][wave*16 + (lane & 15) + kw][(lane >> 4)*8];
      #pragma unroll
      for (int nf = 0; nf < 4; ++nf){
        const ushort* wp = Wb + (size_t)(n0 + nf*16 + (lane & 15))*KTOT
                              + (kh*3 + kw)*CM + c0 + (lane >> 4)*8;
        bf16x8 bb = *(const bf16x8*)wp;
        acc[nf] = __builtin_amdgcn_mfma_f32_16x16x32_bf16(a, bb, acc[nf], 0, 0, 0);
      }
    }
    __syncthreads();
  }

  int mrow = wave*16 + ((lane >> 4) << 2);
  int w = w0 + mrow;
  #pragma unroll
  for (int nf = 0; nf < 4; ++nf){
    int n = n0 + nf*16 + (lane & 15);
    float r0 = acc[nf][0], r1 = acc[nf][1], r2 = acc[nf][2], r3 = acc[nf][3];
    if (MODE == 0){
      float bb = mb[n];
      r0 += bb; r1 += bb; r2 += bb; r3 += bb;
    } else {
      const float* m3 = mb + (size_t)(b*COUT + n)*3;
      float mL = m3[0], mM = m3[1], mR = m3[2];
      r0 += (w == 0) ? mL : ((w   == WID-1) ? mR : mM);
      r1 += (w+1 == WID-1) ? mR : mM;
      r2 += (w+2 == WID-1) ? mR : mM;
      r3 += (w+3 == WID-1) ? mR : mM;
    }
    r0 = lrelu(r0); r1 = lrelu(r1); r2 = lrelu(r2); r3 = lrelu(r3);
    size_t off = ((size_t)(b*COUT + n)*HOUT + y)*WID + w;
    if (OUTBF){
      ushort4 o = make_ushort4(f2b(r0), f2b(r1), f2b(r2), f2b(r3));
      *(ushort4*)(outh + off) = o;
    } else {
      *(float4*)(outf + off) = make_float4(r0, r1, r2, r3);
    }
  }
}

// ---------------- f32 3x3 conv (small layers), K-split partials ----------------
template<int CM,int CTOT,int HIN,int WID,int COUT,int OPT,int SPLIT>
__global__ void conv3_main1(const float* __restrict__ in,
                            const float* __restrict__ wgt,
                            float* __restrict__ part){
  constexpr int HOUT = HIN - 2;
  constexpr int CSPLIT = CM / SPLIT;
  constexpr int N = 2*COUT*HOUT*WID;
  int hw0 = blockIdx.x*256 + threadIdx.x;
  if (hw0 >= HOUT*WID) return;
  int y = hw0 / WID, w0 = hw0 % WID;
  int b = blockIdx.z;
  int split = blockIdx.y % SPLIT;
  int o0 = (blockIdx.y / SPLIT) * OPT;

  float acc[OPT];
  #pragma unroll
  for (int i=0;i<OPT;i++) acc[i] = 0.f;

  const bool lok = (w0 > 0), rok = (w0 + 1) < WID;
  int c0 = split * CSPLIT;
  for (int c=c0; c<c0+CSPLIT; c++){
    const float* rp = in + ((size_t)(b*CM + c)*HIN + y)*WID + w0;
    #pragma unroll
    for (int kh=0;kh<3;kh++){
      float v0 = lok ? rp[kh*WID - 1] : 0.f;
      float v1 = rp[kh*WID];
      float v2 = rok ? rp[kh*WID + 1] : 0.f;
      #pragma unroll
      for (int i=0;i<OPT;i++){
        const float* wq = wgt + ((size_t)(o0+i)*CTOT + c)*9 + kh*3;
        acc[i] += v0*wq[0] + v1*wq[1] + v2*wq[2];
      }
    }
  }
  #pragma unroll
  for (int i=0;i<OPT;i++)
    part[(size_t)split*N + ((size_t)(b*COUT + o0+i)*HOUT + y)*WID + w0] = acc[i];
}

// ---------------- combine partials + map + lrelu ----------------
template<int SPLIT,int MODE,int COUT,int HOUT,int WID>
__global__ __launch_bounds__(256) void combine_kernel(float* __restrict__ part,
                                                      const float* __restrict__ mapv,
                                                      const float* __restrict__ bias){
  constexpr int N = 2*COUT*HOUT*WID;
  int idx = (blockIdx.x*256 + threadIdx.x)*4;
  if (idx >= N) return;
  float4 v = *(float4*)(part + idx);
  #pragma unroll
  for (int s=1;s<SPLIT;s++){
    float4 u = *(const float4*)(part + (size_t)s*N + idx);
    v.x += u.x; v.y += u.y; v.z += u.z; v.w += u.w;
  }
  int w = idx % WID;
  int r = idx / WID;
  int bo = r / HOUT;
  int o = bo % COUT, b = bo / COUT;
  float* av = (float*)&v;
  if (MODE == 0){
    float bb = bias[o];
    #pragma unroll
    for (int j=0;j<4;j++) av[j] += bb;
  } else if (MODE == 1){
    const float* m = mapv + (size_t)(b*COUT + o)*3;
    #pragma unroll
    for (int j=0;j<4;j++){
      int wj = w + j;
      av[j] += (wj == 0) ? m[0] : ((wj == WID-1) ? m[2] : m[1]);
    }
  } else {
    const float* m = mapv + ((size_t)(b*COUT + o))*WID + w;
    #pragma unroll
    for (int j=0;j<4;j++) av[j] += m[j];
  }
  #pragma unroll
  for (int j=0;j<4;j++) av[j] = lrelu(av[j]);
  *(float4*)(part + idx) = v;
}

// ---------------- 3-value style map ----------------
template<int CS,int CTOT,int COUT,int COFF>
__global__ void map3_kernel(const float* __restrict__ style,
                            const float* __restrict__ wgt,
                            const float* __restrict__ bias,
                            float* __restrict__ mapv){
  int t = threadIdx.x;
  if (t >= 2*COUT) return;
  int b = t / COUT, o = t % COUT;
  float S0=0.f, S1=0.f, S2=0.f;
  for (int c=0;c<CS;c++){
    float s = style[b*CS + c];
    const float* wq = wgt + ((size_t)o*CTOT + COFF + c)*9;
    S0 += s*(wq[0]+wq[3]+wq[6]);
    S1 += s*(wq[1]+wq[4]+wq[7]);
    S2 += s*(wq[2]+wq[5]+wq[8]);
  }
  float bb = bias[o];
  mapv[t*3+0] = S1+S2+bb;
  mapv[t*3+1] = S0+S1+S2+bb;
  mapv[t*3+2] = S0+S1+bb;
}

// ---------------- A6 column map ----------------
__global__ void map6_kernel(const float* __restrict__ spaced,
                            const float* __restrict__ label,
                            const float* __restrict__ wgt,
                            const float* __restrict__ bias,
                            float* __restrict__ mapv){
  int n = blockIdx.x*256 + threadIdx.x;
  int w = n & 127, o = (n >> 7) & 127, b = n >> 14;
  float a = bias[o];
  #pragma unroll
  for (int t=0;t<3;t++){
    int j = w + t - 1;
    if (j < 0 || j >= 128) continue;
    const float* sp = spaced + (j*2 + b)*32;
    const float* lb = label + (j*2 + b)*80;
    for (int c=0;c<32;c++){
      const float* wq = wgt + ((size_t)o*240 + 128 + c)*9 + t;
      a += sp[c]*(wq[0]+wq[3]+wq[6]);
    }
    for (int c=0;c<80;c++){
      const float* wq = wgt + ((size_t)o*240 + 160 + c)*9 + t;
      a += lb[c]*(wq[0]+wq[3]+wq[6]);
    }
  }
  mapv[n] = a;
}

// ---------------- 2x2 mean pool (f32 -> f32) ----------------
__global__ void pool2_kernel(const float* __restrict__ in, float* __restrict__ out,
                             int H, int W, int total){
  int n = blockIdx.x*256 + threadIdx.x;
  if (n >= total) return;
  int Wo = W >> 1;
  int wo = n % Wo;
  int r = n / Wo;
  int Ho = H >> 1;
  int ho = r % Ho;
  int bc = r / Ho;
  const float* p = in + (bc*H + 2*ho)*W + 2*wo;
  out[n] = 0.25f*(p[0] + p[1] + p[W] + p[W+1]);
}

// ---------------- 2x2 mean pool (f32 -> bf16) ----------------
__global__ void pool2_bf16_kernel(const float* __restrict__ in, ushort* __restrict__ out,
                                  int H, int W, int total){
  int n = blockIdx.x*256 + threadIdx.x;
  if (n >= total) return;
  int Wo = W >> 1;
  int wo = n % Wo;
  int r = n / Wo;
  int Ho = H >> 1;
  int ho = r % Ho;
  int bc = r / Ho;
  const float* p = in + (bc*H + 2*ho)*W + 2*wo;
  out[n] = f2b(0.25f*(p[0] + p[1] + p[W] + p[W+1]));
}

// ---------------- pM ----------------
__global__ __launch_bounds__(256) void fm_kernel(const float* __restrict__ A7,
                          const float* __restrict__ fw,
                          const float* __restrict__ fb,
                          float* __restrict__ out){
  __shared__ float red[4];
  int n = blockIdx.x;
  int b = n >> 6, w = n & 63;
  int c = threadIdx.x;
  float a = 0.f;
  #pragma unroll
  for (int r=0;r<3;r++){
    const float* ip = A7 + ((b*256+c)*3+r)*64;
    const float* wp = fw + (c*3+r)*3;
    #pragma unroll
    for (int kw=0;kw<3;kw++){
      int wi = w + kw - 1;
      if (wi>=0 && wi<64) a += ip[wi]*wp[kw];
    }
  }
  #pragma unroll
  for (int off=32; off>0; off>>=1) a += __shfl_down(a, off, 64);
  if ((threadIdx.x & 63) == 0) red[threadIdx.x>>6] = a;
  __syncthreads();
  if (threadIdx.x == 0) out[n] = red[0]+red[1]+red[2]+red[3] + fb[0];
}

// ---------------- cd conv: lane = 4 input channels (d-contiguous), wave-reduce ----------------
// block = (n, og): og selects 32 of 128 outputs; wave handles 8 outputs.
// Writes pooled feature feat[n][o] directly (bias + lrelu + window-mean fused).
__global__ __launch_bounds__(256) void cd_conv_kernel(
    const float* __restrict__ A7,     // (2,256,3,64)
    const int*   __restrict__ clsb,   // (256)
    const float* __restrict__ Wc,     // (80,128,2304)
    const float* __restrict__ bcv,    // (80,128)
    float* __restrict__ featg)        // (256,128)
{
  int blk = blockIdx.x;               // 1024 = n*4 + og
  int n = blk >> 2, og = blk & 3;
  int b = n >> 7, t = n & 127;
  int e = clsb[n];
  int idx = t >> 1;
  int tid = threadIdx.x, lane = tid & 63, wave = tid >> 6;

  // per-lane patch: channels c0..c0+3, all (r, j) — 60 registers, static indices
  float pr[4][3][5];
  int c0 = lane * 4;
  #pragma unroll
  for (int c = 0; c < 4; ++c)
    #pragma unroll
    for (int r = 0; r < 3; ++r){
      const float* ip = A7 + ((size_t)((b*256 + c0 + c)*3) + r)*64;
      #pragma unroll
      for (int j = 0; j < 5; ++j){
        int col = idx - 2 + j;
        pr[c][r][j] = (col >= 0 && col < 64) ? ip[col] : 0.f;
      }
    }

  #pragma unroll 2
  for (int oi = 0; oi < 8; ++oi){
    int o = og*32 + wave*8 + oi;
    const float4* wp = (const float4*)(Wc + ((size_t)e*128 + o)*2304) + lane*9;
    float a0 = 0.f, a1 = 0.f, a2 = 0.f;
    #pragma unroll
    for (int k = 0; k < 9; ++k){
      float4 w4 = wp[k];
      float wv[4] = {w4.x, w4.y, w4.z, w4.w};
      #pragma unroll
      for (int j = 0; j < 4; ++j){
        constexpr int unused = 0; (void)unused;
        int dd = k*4 + j;            // compile-time after unroll
        int c  = dd / 9;
        int rem= dd % 9;
        int r  = rem / 3;
        int kw = rem % 3;
        float wvv = wv[j];
        a0 += wvv * pr[c][r][kw];
        a1 += wvv * pr[c][r][kw+1];
        a2 += wvv * pr[c][r][kw+2];
      }
    }
    #pragma unroll
    for (int off = 32; off > 0; off >>= 1){
      a0 += __shfl_down(a0, off, 64);
      a1 += __shfl_down(a1, off, 64);
      a2 += __shfl_down(a2, off, 64);
    }
    if (lane == 0){
      float bb = bcv[e*128 + o];
      featg[(size_t)n*128 + o] =
        (lrelu(a0+bb) + lrelu(a1+bb) + lrelu(a2+bb)) * (1.f/3.f);
    }
  }
}

// ---------------- cd tail: feat -> fc1 -> fc2 ----------------
__global__ __launch_bounds__(128) void cd_tail_kernel(
    const float* __restrict__ featg,  // (256,128)
    const int*   __restrict__ clsb,
    const float* __restrict__ cstyle, // (2,80,32)
    const float* __restrict__ W1,     // (80,160,128)
    const float* __restrict__ b1,     // (80,128)
    const float* __restrict__ W2,     // (80,128,1)
    const float* __restrict__ b2,     // (80,1)
    float* __restrict__ pChar)        // (256)
{
  __shared__ float feat[160];
  __shared__ float red2[2];
  int n = blockIdx.x, tid = threadIdx.x;
  int b = n >> 7;
  int e = clsb[n];
  int o = tid;
  feat[o] = featg[(size_t)n*128 + o];
  if (tid < 32) feat[128+tid] = cstyle[(b*80 + e)*32 + tid];
  __syncthreads();

  float s = b1[e*128 + o];
  for (int d=0;d<160;d++) s += feat[d]*W1[(e*160 + d)*128 + o];
  float h = s > 0.f ? s : 0.f;
  float contrib = h * W2[e*128 + o];
  #pragma unroll
  for (int off=32; off>0; off>>=1) contrib += __shfl_down(contrib, off, 64);
  if ((tid & 63) == 0) red2[tid>>6] = contrib;
  __syncthreads();
  if (tid == 0) pChar[n] = red2[0] + red2[1] + b2[e];
}

extern "C" void kernel_launch(void* const* d_in, const int* in_sizes, int n_in,
                              void* d_out, int out_size, void* d_ws, size_t ws_size,
                              hipStream_t stream){
  (void)in_sizes; (void)n_in; (void)out_size; (void)ws_size;
  const float* x      = (const float*)d_in[0];
  const float* label  = (const float*)d_in[1];
  const float* g_style= (const float*)d_in[2];
  const float* spaced = (const float*)d_in[3];
  const float* cstyle = (const float*)d_in[4];
  const float* sp1    = (const float*)d_in[5];
  const float* sp2    = (const float*)d_in[6];
  const float* in_w   = (const float*)d_in[7];
  const float* in_b   = (const float*)d_in[8];
  const float* c1w1   = (const float*)d_in[9];
  const float* c1b1   = (const float*)d_in[10];
  const float* c1w2   = (const float*)d_in[11];
  const float* c1b2   = (const float*)d_in[12];
  const float* c2w    = (const float*)d_in[13];
  const float* c2b    = (const float*)d_in[14];
  const float* c3w1   = (const float*)d_in[15];
  const float* c3b1   = (const float*)d_in[16];
  const float* c3w2   = (const float*)d_in[17];
  const float* c3b2   = (const float*)d_in[18];
  const float* fm_w   = (const float*)d_in[19];
  const float* fm_b   = (const float*)d_in[20];
  const float* cdw    = (const float*)d_in[21];
  const float* cdb    = (const float*)d_in[22];
  const float* fc1w   = (const float*)d_in[23];
  const float* fc1b   = (const float*)d_in[24];
  const float* fc2w   = (const float*)d_in[25];
  const float* fc2b   = (const float*)d_in[26];
  float* out = (float*)d_out;
  char* ws = (char*)d_ws;

  ushort* h1b = (ushort*)(ws + 0);                 // 7,602,176
  float*  A2  = (float*) (ws + 7602176);           // 14,680,064
  ushort* P3b = (ushort*)(ws + 22282240);          // 1,835,008
  ushort* A4b = (ushort*)(ws + 24117248);          // 3,407,872
  float*  A5  = (float*) (ws + 27525120);          // 6,291,456
  float*  P5  = (float*) (ws + 33816576);          // 1,572,864
  float*  A6p = (float*) (ws + 35389440);          // 10,485,760 (8 splits)
  float*  P6  = (float*) (ws + 45875200);          // 327,680
  float*  A7p = (float*) (ws + 46202880);          // 3,145,728 (8 splits)
  float*  featg=(float*) (ws + 49348608);          // 131,072
  ushort* Wb2 = (ushort*)(ws + 52494336);          // 73,728
  ushort* Wb4 = (ushort*)(ws + 52568064);          // 147,456
  ushort* Wb5 = (ushort*)(ws + 52715520);          // 294,912
  float*  map6= (float*) (ws + 53010432);          // 131,072
  float*  map1= (float*) (ws + 53141504);          // 1,536
  float*  map2= (float*) (ws + 53143040);          // 3,072
  float*  s1  = (float*) (ws + 53146112);
  float*  s2  = (float*) (ws + 53146368);
  int*    clsb= (int*)   (ws + 53146880);

  style_kernel<<<1,256,0,stream>>>(g_style, sp1, sp2, s1, s2);
  cls_kernel<<<1,256,0,stream>>>(label, clsb);
  map3_kernel<32,96,64,64><<<1,128,0,stream>>>(s1, c1w1, c1b1, map1);
  map3_kernel<64,192,128,128><<<1,256,0,stream>>>(s2, c2w, c2b, map2);
  map6_kernel<<<128,256,0,stream>>>(spaced, label, c3w1, c3b1, map6);
  repack_kernel<64,96,64><<<144,256,0,stream>>>(c1w1, Wb2);
  repack_kernel<64,64,128><<<288,256,0,stream>>>(c1w2, Wb4);
  repack_kernel<128,192,128><<<576,256,0,stream>>>(c2w, Wb5);

  // h1 (bf16)
  conv_in_kernel<<<dim3(116,8,2),256,0,stream>>>(x, in_w, in_b, h1b);
  // A2 = lrelu(conv(h1) + map1) : MFMA, f32 out
  conv_mfma<64,512,58,64,1,0><<<dim3(448,1,2),256,0,stream>>>(h1b, Wb2, map1, A2, nullptr);
  // P3 (bf16)
  pool2_bf16_kernel<<<3584,256,0,stream>>>(A2, P3b, 56, 512, 917504);
  // A4 = lrelu(conv(P3) + b) : MFMA, bf16 out
  conv_mfma<64,256,28,128,0,1><<<dim3(104,2,2),256,0,stream>>>(P3b, Wb4, c1b2, nullptr, A4b);
  // A5 = lrelu(conv(A4) + map2) : MFMA, f32 out
  conv_mfma<128,256,26,128,1,0><<<dim3(96,2,2),256,0,stream>>>(A4b, Wb5, map2, A5, nullptr);
  // P5
  pool2_kernel<<<1536,256,0,stream>>>(A5, P5, 24, 256, 393216);
  // A6 (f32 path)
  conv3_main1<128,240,12,128,128,8,8><<<dim3(5,16*8,2),256,0,stream>>>(P5, c3w1, A6p);
  combine_kernel<8,2,128,10,128><<<320,256,0,stream>>>(A6p, map6, nullptr);
  // P6
  pool2_kernel<<<320,256,0,stream>>>(A6p, P6, 10, 128, 81920);
  // A7 (f32 path)
  conv3_main1<128,128,5,64,256,4,8><<<dim3(1,64*8,2),256,0,stream>>>(P6, c3w2, A7p);
  combine_kernel<8,0,256,3,64><<<96,256,0,stream>>>(A7p, nullptr, c3b2);
  // pM
  fm_kernel<<<128,256,0,stream>>>(A7p, fm_w, fm_b, out);
  // pChar
  cd_conv_kernel<<<1024,256,0,stream>>>(A7p, clsb, cdw, cdb, featg);
  cd_tail_kernel<<<256,128,0,stream>>>(featg, clsb, cstyle, fc1w, fc1b, fc2w, fc2b, out + 128);
}

// Round 8
// 332.340 us; speedup vs baseline: 1.0639x; 1.0639x over previous
//
#include <hip/hip_runtime.h>
#include <hip/hip_bf16.h>

#define LEAKC 0.1f

__device__ __forceinline__ float lrelu(float v){ return v > 0.f ? v : LEAKC*v; }
__device__ __forceinline__ ushort f2b(float f){
  __hip_bfloat16 h = __float2bfloat16(f);
  return *reinterpret_cast<ushort*>(&h);
}

typedef __attribute__((ext_vector_type(8))) short bf16x8;
typedef __attribute__((ext_vector_type(4))) float f32x4;

// ---------------- styles ----------------
__global__ void style_kernel(const float* __restrict__ g,
                             const float* __restrict__ sp1,
                             const float* __restrict__ sp2,
                             float* __restrict__ s1, float* __restrict__ s2){
  int t = threadIdx.x;
  if (t < 64){
    int b = t >> 5, j = t & 31;
    float a = 0.f;
    for (int k=0;k<256;k++) a += g[b*256+k]*sp1[j*256+k];
    s1[t] = a;
  } else if (t < 192){
    int u = t - 64;
    int b = u >> 6, j = u & 63;
    float a = 0.f;
    for (int k=0;k<256;k++) a += g[b*256+k]*sp2[j*256+k];
    s2[u] = a;
  }
}

// ---------------- cls ----------------
__global__ void cls_kernel(const float* __restrict__ label, int* __restrict__ cls){
  int n = threadIdx.x;
  int b = n >> 7, t = n & 127;
  const float* p = label + (t*2 + b)*80;
  float best = p[0]; int bi = 0;
  for (int c=1;c<80;c++){ float v = p[c]; if (v > best){ best = v; bi = c; } }
  cls[n] = bi;
}

// ---------------- input conv 7x7 -> bf16 out ----------------
__global__ void conv_in_kernel(const float* __restrict__ x,
                               const float* __restrict__ wgt,
                               const float* __restrict__ bias,
                               ushort* __restrict__ out){
  int hw = blockIdx.x*256 + threadIdx.x;
  int y = hw >> 9, w = hw & 511;
  int b = blockIdx.z;
  int o0 = blockIdx.y * 8;
  float acc[8];
  #pragma unroll
  for (int i=0;i<8;i++) acc[i] = bias[o0+i];
  for (int kh=0;kh<7;kh++){
    const float* ip = x + (b*64 + y + kh)*512;
    #pragma unroll
    for (int kw=0;kw<7;kw++){
      int wi = w + kw - 3;
      float v = (wi>=0 && wi<512) ? ip[wi] : 0.f;
      #pragma unroll
      for (int i=0;i<8;i++) acc[i] += v * wgt[(o0+i)*49 + kh*7 + kw];
    }
  }
  #pragma unroll
  for (int i=0;i<8;i++)
    out[((b*64 + o0+i)*58 + y)*512 + w] = f2b(lrelu(acc[i]));
}

// ---------------- weight repack: wb[n][(kh*3+kw)*CM + c] = bf16(w[n][c][kh][kw]) ----------------
template<int CM,int CTOT,int COUT>
__global__ void repack_kernel(const float* __restrict__ w, ushort* __restrict__ wb){
  int i = blockIdx.x*256 + threadIdx.x;
  if (i >= COUT*9*CM) return;
  int c = i % CM; int r = i / CM; int t = r % 9; int n = r / 9;
  wb[i] = f2b(w[((size_t)n*CTOT + c)*9 + t]);
}

// ---------------- MFMA conv: 3x3, pad(0,1), BM=64 (one w-strip), BN=64, K=CM*9 ----------------
template<int CM,int WID,int HIN,int COUT,int MODE,int OUTBF>
__global__ __launch_bounds__(256) void conv_mfma(
    const ushort* __restrict__ in,   // bf16 (2,CM,HIN,WID)
    const ushort* __restrict__ Wb,   // bf16 (COUT, CM*9)
    const float*  __restrict__ mb,   // map (2,COUT,3) or bias (COUT)
    float* __restrict__ outf,
    ushort* __restrict__ outh){
  constexpr int HOUT = HIN - 2;
  constexpr int KTOT = CM*9;
  constexpr int SLABS = CM/32;
  constexpr int NST = 3*SLABS;
  __shared__ ushort A[2][66][40];
  int tid = threadIdx.x, lane = tid & 63, wave = tid >> 6;
  int mt = blockIdx.x;
  int y  = mt / (WID/64), w0 = (mt % (WID/64))*64;
  int n0 = blockIdx.y*64;
  int b  = blockIdx.z;

  f32x4 acc[4];
  #pragma unroll
  for (int nf=0;nf<4;nf++) acc[nf] = (f32x4){0.f,0.f,0.f,0.f};

  auto stage = [&](int s, int bufi){
    int kh = s / SLABS;
    int c0 = (s % SLABS)*32;
    const ushort* base = in + ((size_t)(b*CM + c0)*HIN + (y+kh))*WID;
    int c2 = (tid & 15)*2, m0v = (tid >> 4)*2*2;
    const ushort* p0 = base + (size_t)c2*HIN*WID + w0 + m0v;
    const ushort* p1 = p0 + (size_t)HIN*WID;
    ushort4 va = *(const ushort4*)p0;
    ushort4 vb = *(const ushort4*)p1;
    uint* dst = (uint*)&A[bufi][1+m0v][c2];
    dst[0]  = (uint)va.x | ((uint)vb.x << 16);
    dst[20] = (uint)va.y | ((uint)vb.y << 16);
    dst[40] = (uint)va.z | ((uint)vb.z << 16);
    dst[60] = (uint)va.w | ((uint)vb.w << 16);
    if (tid < 64){
      int c = tid & 31, side = tid >> 5;
      int w = side ? (w0 + 64) : (w0 - 1);
      ushort v = 0;
      if (w >= 0 && w < WID) v = base[(size_t)c*HIN*WID + w];
      A[bufi][side ? 65 : 0][c] = v;
    }
  };

  stage(0, 0);
  __syncthreads();
  for (int s = 0; s < NST; ++s){
    int cur = s & 1;
    if (s + 1 < NST) stage(s+1, cur ^ 1);
    int kh = s / SLABS;
    int c0 = (s % SLABS)*32;
    #pragma unroll
    for (int kw = 0; kw < 3; ++kw){
      bf16x8 a = *(bf16x8*)&A[cur][wave*16 + (lane & 15) + kw][(lane >> 4)*8];
      #pragma unroll
      for (int nf = 0; nf < 4; ++nf){
        const ushort* wp = Wb + (size_t)(n0 + nf*16 + (lane & 15))*KTOT
                              + (kh*3 + kw)*CM + c0 + (lane >> 4)*8;
        bf16x8 bb = *(const bf16x8*)wp;
        acc[nf] = __builtin_amdgcn_mfma_f32_16x16x32_bf16(a, bb, acc[nf], 0, 0, 0);
      }
    }
    __syncthreads();
  }

  int mrow = wave*16 + ((lane >> 4) << 2);
  int w = w0 + mrow;
  #pragma unroll
  for (int nf = 0; nf < 4; ++nf){
    int n = n0 + nf*16 + (lane & 15);
    float r0 = acc[nf][0], r1 = acc[nf][1], r2 = acc[nf][2], r3 = acc[nf][3];
    if (MODE == 0){
      float bb = mb[n];
      r0 += bb; r1 += bb; r2 += bb; r3 += bb;
    } else {
      const float* m3 = mb + (size_t)(b*COUT + n)*3;
      float mL = m3[0], mM = m3[1], mR = m3[2];
      r0 += (w == 0) ? mL : ((w   == WID-1) ? mR : mM);
      r1 += (w+1 == WID-1) ? mR : mM;
      r2 += (w+2 == WID-1) ? mR : mM;
      r3 += (w+3 == WID-1) ? mR : mM;
    }
    r0 = lrelu(r0); r1 = lrelu(r1); r2 = lrelu(r2); r3 = lrelu(r3);
    size_t off = ((size_t)(b*COUT + n)*HOUT + y)*WID + w;
    if (OUTBF){
      ushort4 o = make_ushort4(f2b(r0), f2b(r1), f2b(r2), f2b(r3));
      *(ushort4*)(outh + off) = o;
    } else {
      *(float4*)(outf + off) = make_float4(r0, r1, r2, r3);
    }
  }
}

// ---------------- f32 3x3 conv (small layers), K-split partials ----------------
template<int CM,int CTOT,int HIN,int WID,int COUT,int OPT,int SPLIT>
__global__ void conv3_main1(const float* __restrict__ in,
                            const float* __restrict__ wgt,
                            float* __restrict__ part){
  constexpr int HOUT = HIN - 2;
  constexpr int CSPLIT = CM / SPLIT;
  constexpr int N = 2*COUT*HOUT*WID;
  int hw0 = blockIdx.x*256 + threadIdx.x;
  if (hw0 >= HOUT*WID) return;
  int y = hw0 / WID, w0 = hw0 % WID;
  int b = blockIdx.z;
  int split = blockIdx.y % SPLIT;
  int o0 = (blockIdx.y / SPLIT) * OPT;

  float acc[OPT];
  #pragma unroll
  for (int i=0;i<OPT;i++) acc[i] = 0.f;

  const bool lok = (w0 > 0), rok = (w0 + 1) < WID;
  int c0 = split * CSPLIT;
  for (int c=c0; c<c0+CSPLIT; c++){
    const float* rp = in + ((size_t)(b*CM + c)*HIN + y)*WID + w0;
    #pragma unroll
    for (int kh=0;kh<3;kh++){
      float v0 = lok ? rp[kh*WID - 1] : 0.f;
      float v1 = rp[kh*WID];
      float v2 = rok ? rp[kh*WID + 1] : 0.f;
      #pragma unroll
      for (int i=0;i<OPT;i++){
        const float* wq = wgt + ((size_t)(o0+i)*CTOT + c)*9 + kh*3;
        acc[i] += v0*wq[0] + v1*wq[1] + v2*wq[2];
      }
    }
  }
  #pragma unroll
  for (int i=0;i<OPT;i++)
    part[(size_t)split*N + ((size_t)(b*COUT + o0+i)*HOUT + y)*WID + w0] = acc[i];
}

// ---------------- combine partials + map + lrelu ----------------
template<int SPLIT,int MODE,int COUT,int HOUT,int WID>
__global__ __launch_bounds__(256) void combine_kernel(float* __restrict__ part,
                                                      const float* __restrict__ mapv,
                                                      const float* __restrict__ bias){
  constexpr int N = 2*COUT*HOUT*WID;
  int idx = (blockIdx.x*256 + threadIdx.x)*4;
  if (idx >= N) return;
  float4 v = *(float4*)(part + idx);
  #pragma unroll
  for (int s=1;s<SPLIT;s++){
    float4 u = *(const float4*)(part + (size_t)s*N + idx);
    v.x += u.x; v.y += u.y; v.z += u.z; v.w += u.w;
  }
  int w = idx % WID;
  int r = idx / WID;
  int bo = r / HOUT;
  int o = bo % COUT, b = bo / COUT;
  float* av = (float*)&v;
  if (MODE == 0){
    float bb = bias[o];
    #pragma unroll
    for (int j=0;j<4;j++) av[j] += bb;
  } else if (MODE == 1){
    const float* m = mapv + (size_t)(b*COUT + o)*3;
    #pragma unroll
    for (int j=0;j<4;j++){
      int wj = w + j;
      av[j] += (wj == 0) ? m[0] : ((wj == WID-1) ? m[2] : m[1]);
    }
  } else {
    const float* m = mapv + ((size_t)(b*COUT + o))*WID + w;
    #pragma unroll
    for (int j=0;j<4;j++) av[j] += m[j];
  }
  #pragma unroll
  for (int j=0;j<4;j++) av[j] = lrelu(av[j]);
  *(float4*)(part + idx) = v;
}

// ---------------- 3-value style map ----------------
template<int CS,int CTOT,int COUT,int COFF>
__global__ void map3_kernel(const float* __restrict__ style,
                            const float* __restrict__ wgt,
                            const float* __restrict__ bias,
                            float* __restrict__ mapv){
  int t = threadIdx.x;
  if (t >= 2*COUT) return;
  int b = t / COUT, o = t % COUT;
  float S0=0.f, S1=0.f, S2=0.f;
  for (int c=0;c<CS;c++){
    float s = style[b*CS + c];
    const float* wq = wgt + ((size_t)o*CTOT + COFF + c)*9;
    S0 += s*(wq[0]+wq[3]+wq[6]);
    S1 += s*(wq[1]+wq[4]+wq[7]);
    S2 += s*(wq[2]+wq[5]+wq[8]);
  }
  float bb = bias[o];
  mapv[t*3+0] = S1+S2+bb;
  mapv[t*3+1] = S0+S1+S2+bb;
  mapv[t*3+2] = S0+S1+bb;
}

// ---------------- A6 column map ----------------
__global__ void map6_kernel(const float* __restrict__ spaced,
                            const float* __restrict__ label,
                            const float* __restrict__ wgt,
                            const float* __restrict__ bias,
                            float* __restrict__ mapv){
  int n = blockIdx.x*256 + threadIdx.x;
  int w = n & 127, o = (n >> 7) & 127, b = n >> 14;
  float a = bias[o];
  #pragma unroll
  for (int t=0;t<3;t++){
    int j = w + t - 1;
    if (j < 0 || j >= 128) continue;
    const float* sp = spaced + (j*2 + b)*32;
    const float* lb = label + (j*2 + b)*80;
    for (int c=0;c<32;c++){
      const float* wq = wgt + ((size_t)o*240 + 128 + c)*9 + t;
      a += sp[c]*(wq[0]+wq[3]+wq[6]);
    }
    for (int c=0;c<80;c++){
      const float* wq = wgt + ((size_t)o*240 + 160 + c)*9 + t;
      a += lb[c]*(wq[0]+wq[3]+wq[6]);
    }
  }
  mapv[n] = a;
}

// ---------------- 2x2 mean pool (f32 -> f32) ----------------
__global__ void pool2_kernel(const float* __restrict__ in, float* __restrict__ out,
                             int H, int W, int total){
  int n = blockIdx.x*256 + threadIdx.x;
  if (n >= total) return;
  int Wo = W >> 1;
  int wo = n % Wo;
  int r = n / Wo;
  int Ho = H >> 1;
  int ho = r % Ho;
  int bc = r / Ho;
  const float* p = in + (bc*H + 2*ho)*W + 2*wo;
  out[n] = 0.25f*(p[0] + p[1] + p[W] + p[W+1]);
}

// ---------------- 2x2 mean pool (f32 -> bf16) ----------------
__global__ void pool2_bf16_kernel(const float* __restrict__ in, ushort* __restrict__ out,
                                  int H, int W, int total){
  int n = blockIdx.x*256 + threadIdx.x;
  if (n >= total) return;
  int Wo = W >> 1;
  int wo = n % Wo;
  int r = n / Wo;
  int Ho = H >> 1;
  int ho = r % Ho;
  int bc = r / Ho;
  const float* p = in + (bc*H + 2*ho)*W + 2*wo;
  out[n] = f2b(0.25f*(p[0] + p[1] + p[W] + p[W+1]));
}

// ---------------- pM ----------------
__global__ __launch_bounds__(256) void fm_kernel(const float* __restrict__ A7,
                          const float* __restrict__ fw,
                          const float* __restrict__ fb,
                          float* __restrict__ out){
  __shared__ float red[4];
  int n = blockIdx.x;
  int b = n >> 6, w = n & 63;
  int c = threadIdx.x;
  float a = 0.f;
  #pragma unroll
  for (int r=0;r<3;r++){
    const float* ip = A7 + ((b*256+c)*3+r)*64;
    const float* wp = fw + (c*3+r)*3;
    #pragma unroll
    for (int kw=0;kw<3;kw++){
      int wi = w + kw - 1;
      if (wi>=0 && wi<64) a += ip[wi]*wp[kw];
    }
  }
  #pragma unroll
  for (int off=32; off>0; off>>=1) a += __shfl_down(a, off, 64);
  if ((threadIdx.x & 63) == 0) red[threadIdx.x>>6] = a;
  __syncthreads();
  if (threadIdx.x == 0) out[n] = red[0]+red[1]+red[2]+red[3] + fb[0];
}

// ---------------- cd conv: wave cooperatively reads ONE output's weights (coalesced) ----------------
// block = (n, og); LDS pw[j][d] = patch value for window j, weight-dim d.
// Per output: 9 coalesced float4 wave-loads + 27 ds_read_b128 + 108 FMA + shfl reduce.
__global__ __launch_bounds__(256) void cd_conv_kernel(
    const float* __restrict__ A7,     // (2,256,3,64)
    const int*   __restrict__ clsb,   // (256)
    const float* __restrict__ Wc,     // (80,128,2304)
    const float* __restrict__ bcv,    // (80,128)
    float* __restrict__ featg)        // (256,128)
{
  __shared__ float pw[3][2304];       // 27,648 B
  int blk = blockIdx.x;               // 1024 = n*4 + og
  int n = blk >> 2, og = blk & 3;
  int b = n >> 7, t = n & 127;
  int e = clsb[n];
  int idx = t >> 1;
  int tid = threadIdx.x, lane = tid & 63, wave = tid >> 6;

  for (int i = tid; i < 3*2304; i += 256){
    int j = i / 2304, d = i - j*2304;
    int c = d / 9, rem = d - c*9;
    int r = rem / 3, kw = rem - r*3;
    int col = idx - 2 + kw + j;
    pw[j][d] = (col >= 0 && col < 64) ? A7[((size_t)(b*256 + c)*3 + r)*64 + col] : 0.f;
  }
  __syncthreads();

  #pragma unroll 2
  for (int oi = 0; oi < 8; ++oi){
    int o = og*32 + wave*8 + oi;
    const float4* wp = (const float4*)(Wc + ((size_t)e*128 + o)*2304);
    float a0 = 0.f, a1 = 0.f, a2 = 0.f;
    #pragma unroll
    for (int k = 0; k < 9; ++k){
      float4 w4 = wp[k*64 + lane];
      int d0 = (k*64 + lane)*4;
      float4 p0 = *(const float4*)&pw[0][d0];
      float4 p1 = *(const float4*)&pw[1][d0];
      float4 p2 = *(const float4*)&pw[2][d0];
      a0 += w4.x*p0.x + w4.y*p0.y + w4.z*p0.z + w4.w*p0.w;
      a1 += w4.x*p1.x + w4.y*p1.y + w4.z*p1.z + w4.w*p1.w;
      a2 += w4.x*p2.x + w4.y*p2.y + w4.z*p2.z + w4.w*p2.w;
    }
    #pragma unroll
    for (int off = 32; off > 0; off >>= 1){
      a0 += __shfl_down(a0, off, 64);
      a1 += __shfl_down(a1, off, 64);
      a2 += __shfl_down(a2, off, 64);
    }
    if (lane == 0){
      float bb = bcv[e*128 + o];
      featg[(size_t)n*128 + o] =
        (lrelu(a0+bb) + lrelu(a1+bb) + lrelu(a2+bb)) * (1.f/3.f);
    }
  }
}

// ---------------- cd tail: feat -> fc1 -> fc2 ----------------
__global__ __launch_bounds__(128) void cd_tail_kernel(
    const float* __restrict__ featg,  // (256,128)
    const int*   __restrict__ clsb,
    const float* __restrict__ cstyle, // (2,80,32)
    const float* __restrict__ W1,     // (80,160,128)
    const float* __restrict__ b1,     // (80,128)
    const float* __restrict__ W2,     // (80,128,1)
    const float* __restrict__ b2,     // (80,1)
    float* __restrict__ pChar)        // (256)
{
  __shared__ float feat[160];
  __shared__ float red2[2];
  int n = blockIdx.x, tid = threadIdx.x;
  int b = n >> 7;
  int e = clsb[n];
  int o = tid;
  feat[o] = featg[(size_t)n*128 + o];
  if (tid < 32) feat[128+tid] = cstyle[(b*80 + e)*32 + tid];
  __syncthreads();

  float s = b1[e*128 + o];
  for (int d=0;d<160;d++) s += feat[d]*W1[(e*160 + d)*128 + o];
  float h = s > 0.f ? s : 0.f;
  float contrib = h * W2[e*128 + o];
  #pragma unroll
  for (int off=32; off>0; off>>=1) contrib += __shfl_down(contrib, off, 64);
  if ((tid & 63) == 0) red2[tid>>6] = contrib;
  __syncthreads();
  if (tid == 0) pChar[n] = red2[0] + red2[1] + b2[e];
}

extern "C" void kernel_launch(void* const* d_in, const int* in_sizes, int n_in,
                              void* d_out, int out_size, void* d_ws, size_t ws_size,
                              hipStream_t stream){
  (void)in_sizes; (void)n_in; (void)out_size; (void)ws_size;
  const float* x      = (const float*)d_in[0];
  const float* label  = (const float*)d_in[1];
  const float* g_style= (const float*)d_in[2];
  const float* spaced = (const float*)d_in[3];
  const float* cstyle = (const float*)d_in[4];
  const float* sp1    = (const float*)d_in[5];
  const float* sp2    = (const float*)d_in[6];
  const float* in_w   = (const float*)d_in[7];
  const float* in_b   = (const float*)d_in[8];
  const float* c1w1   = (const float*)d_in[9];
  const float* c1b1   = (const float*)d_in[10];
  const float* c1w2   = (const float*)d_in[11];
  const float* c1b2   = (const float*)d_in[12];
  const float* c2w    = (const float*)d_in[13];
  const float* c2b    = (const float*)d_in[14];
  const float* c3w1   = (const float*)d_in[15];
  const float* c3b1   = (const float*)d_in[16];
  const float* c3w2   = (const float*)d_in[17];
  const float* c3b2   = (const float*)d_in[18];
  const float* fm_w   = (const float*)d_in[19];
  const float* fm_b   = (const float*)d_in[20];
  const float* cdw    = (const float*)d_in[21];
  const float* cdb    = (const float*)d_in[22];
  const float* fc1w   = (const float*)d_in[23];
  const float* fc1b   = (const float*)d_in[24];
  const float* fc2w   = (const float*)d_in[25];
  const float* fc2b   = (const float*)d_in[26];
  float* out = (float*)d_out;
  char* ws = (char*)d_ws;

  ushort* h1b = (ushort*)(ws + 0);                 // 7,602,176
  float*  A2  = (float*) (ws + 7602176);           // 14,680,064
  ushort* P3b = (ushort*)(ws + 22282240);          // 1,835,008
  ushort* A4b = (ushort*)(ws + 24117248);          // 3,407,872
  float*  A5  = (float*) (ws + 27525120);          // 6,291,456
  float*  P5  = (float*) (ws + 33816576);          // 1,572,864
  float*  A6p = (float*) (ws + 35389440);          // 10,485,760 (8 splits)
  float*  P6  = (float*) (ws + 45875200);          // 327,680
  float*  A7p = (float*) (ws + 46202880);          // 3,145,728 (8 splits)
  float*  featg=(float*) (ws + 49348608);          // 131,072
  ushort* Wb2 = (ushort*)(ws + 52494336);          // 73,728
  ushort* Wb4 = (ushort*)(ws + 52568064);          // 147,456
  ushort* Wb5 = (ushort*)(ws + 52715520);          // 294,912
  float*  map6= (float*) (ws + 53010432);          // 131,072
  float*  map1= (float*) (ws + 53141504);          // 1,536
  float*  map2= (float*) (ws + 53143040);          // 3,072
  float*  s1  = (float*) (ws + 53146112);
  float*  s2  = (float*) (ws + 53146368);
  int*    clsb= (int*)   (ws + 53146880);

  style_kernel<<<1,256,0,stream>>>(g_style, sp1, sp2, s1, s2);
  cls_kernel<<<1,256,0,stream>>>(label, clsb);
  map3_kernel<32,96,64,64><<<1,128,0,stream>>>(s1, c1w1, c1b1, map1);
  map3_kernel<64,192,128,128><<<1,256,0,stream>>>(s2, c2w, c2b, map2);
  map6_kernel<<<128,256,0,stream>>>(spaced, label, c3w1, c3b1, map6);
  repack_kernel<64,96,64><<<144,256,0,stream>>>(c1w1, Wb2);
  repack_kernel<64,64,128><<<288,256,0,stream>>>(c1w2, Wb4);
  repack_kernel<128,192,128><<<576,256,0,stream>>>(c2w, Wb5);

  // h1 (bf16)
  conv_in_kernel<<<dim3(116,8,2),256,0,stream>>>(x, in_w, in_b, h1b);
  // A2 = lrelu(conv(h1) + map1) : MFMA, f32 out
  conv_mfma<64,512,58,64,1,0><<<dim3(448,1,2),256,0,stream>>>(h1b, Wb2, map1, A2, nullptr);
  // P3 (bf16)
  pool2_bf16_kernel<<<3584,256,0,stream>>>(A2, P3b, 56, 512, 917504);
  // A4 = lrelu(conv(P3) + b) : MFMA, bf16 out
  conv_mfma<64,256,28,128,0,1><<<dim3(104,2,2),256,0,stream>>>(P3b, Wb4, c1b2, nullptr, A4b);
  // A5 = lrelu(conv(A4) + map2) : MFMA, f32 out
  conv_mfma<128,256,26,128,1,0><<<dim3(96,2,2),256,0,stream>>>(A4b, Wb5, map2, A5, nullptr);
  // P5
  pool2_kernel<<<1536,256,0,stream>>>(A5, P5, 24, 256, 393216);
  // A6 (f32 path)
  conv3_main1<128,240,12,128,128,8,8><<<dim3(5,16*8,2),256,0,stream>>>(P5, c3w1, A6p);
  combine_kernel<8,2,128,10,128><<<320,256,0,stream>>>(A6p, map6, nullptr);
  // P6
  pool2_kernel<<<320,256,0,stream>>>(A6p, P6, 10, 128, 81920);
  // A7 (f32 path)
  conv3_main1<128,128,5,64,256,4,8><<<dim3(1,64*8,2),256,0,stream>>>(P6, c3w2, A7p);
  combine_kernel<8,0,256,3,64><<<96,256,0,stream>>>(A7p, nullptr, c3b2);
  // pM
  fm_kernel<<<128,256,0,stream>>>(A7p, fm_w, fm_b, out);
  // pChar
  cd_conv_kernel<<<1024,256,0,stream>>>(A7p, clsb, cdw, cdb, featg);
  cd_tail_kernel<<<256,128,0,stream>>>(featg, clsb, cstyle, fc1w, fc1b, fc2w, fc2b, out + 128);
}